// Round 13
// baseline (1056.968 us; speedup 1.0000x reference)
//
#include <hip/hip_runtime.h>

#define Bdim 64
#define Tdim 512
#define Idim 512
#define Hdim 512
#define CLIPV 10.0f
#define NREGCT 26       // col-tiles whose B-fragments live in registers (208 dwords)
#define NLDSCT 6        // col-tiles in LDS (96 KB)

typedef __attribute__((ext_vector_type(4))) float f32x4;
typedef __attribute__((ext_vector_type(8))) short bf16x8;
typedef _Float16 half2v __attribute__((ext_vector_type(2)));
typedef _Float16 f16x8 __attribute__((ext_vector_type(8)));
typedef __fp16 fp16x2 __attribute__((ext_vector_type(2)));

__device__ __forceinline__ ushort f2bf(float f) {
    unsigned u = __builtin_bit_cast(unsigned, f);
    u += 0x7fffu + ((u >> 16) & 1u);   // round-to-nearest-even
    return (ushort)(u >> 16);
}
__device__ __forceinline__ float bf2f(ushort h) {
    return __builtin_bit_cast(float, (unsigned)h << 16);
}
__device__ __forceinline__ void split_bf(float f, ushort& h, ushort& l) {
    h = f2bf(f);
    l = f2bf(f - bf2f(h));
}
__device__ __forceinline__ uint packf16(float a, float b) {
    _Float16 fa = (_Float16)a, fb = (_Float16)b;
    return (uint)__builtin_bit_cast(ushort, fa) |
           ((uint)__builtin_bit_cast(ushort, fb) << 16);
}
__device__ __forceinline__ uint pkrtz(float a, float b) {
#if __has_builtin(__builtin_amdgcn_cvt_pkrtz)
    fp16x2 p = __builtin_amdgcn_cvt_pkrtz(a, b);
    return __builtin_bit_cast(uint, p);
#else
    return packf16(a, b);
#endif
}
__device__ __forceinline__ float fastrcp(float x) {
#if __has_builtin(__builtin_amdgcn_rcpf)
    return __builtin_amdgcn_rcpf(x);
#else
    return 1.0f / x;
#endif
}

// ---- cast + transpose W into hi/lo bf16 (feed-forward GEMM operands) ----
__global__ __launch_bounds__(256) void transpose_w_kernel(const float* __restrict__ w,
                                                          ushort* __restrict__ wth,
                                                          ushort* __restrict__ wtl) {
    int idx = blockIdx.x * 256 + threadIdx.x;
    int k = idx >> 9, n = idx & 511;
    ushort h, l;
    split_bf(w[idx], h, l);
    wth[n * Idim + k] = h;
    wtl[n * Idim + k] = l;
}

// ---- pack R into MFMA B-fragments (fp16) ----
// frag f = kt*32 + ct (kt: k-tile within wave's k-eighth, ct: 16-col tile).
// Consuming thread t=(w,l): B[k][col] with col = ct*16 + (l&15),
// k = w*64 + kt*32 + (l>>4)*8 + 2q(+e).  rpk[f*2048 + t*4 + q].
__global__ __launch_bounds__(256) void pack_r_kernel(const float* __restrict__ Rw,
                                                     uint* __restrict__ rpk) {
    int d = blockIdx.x * 256 + threadIdx.x;      // 0..131071
    int f = d >> 11;                             // 0..63
    int rem = d & 2047;
    int t = rem >> 2, q = rem & 3;
    int kt = f >> 5, ct = f & 31;
    int w = t >> 6, l = t & 63;
    int col = ct * 16 + (l & 15);
    int k = w * 64 + kt * 32 + (l >> 4) * 8 + 2 * q;
    rpk[d] = packf16(Rw[(size_t)k * Hdim + col],
                     Rw[(size_t)(k + 1) * Hdim + col]);
}

// ---- phase 1: pre = x @ W + bias via bf16x3 MFMA ----
#define BM 128
#define BN 128
#define BK 32
__global__ __launch_bounds__(256) void gemm_xw(
    const float* __restrict__ A,
    const ushort* __restrict__ Bth,
    const ushort* __restrict__ Btl,
    const float* __restrict__ bias,
    float* __restrict__ C,
    int M, int N, int K)
{
    __shared__ ushort AsH[BM][BK];
    __shared__ ushort AsL[BM][BK];
    __shared__ ushort BsH[BN][BK];
    __shared__ ushort BsL[BN][BK];
    int bm = blockIdx.x, bn = blockIdx.y;
    int tid = threadIdx.x;
    int wave = tid >> 6, lane = tid & 63;
    int wr = wave >> 1, wc = wave & 1;
    f32x4 acc[4][4] = {};
    const int row0 = bm * BM, col0 = bn * BN;
    const int sr = tid >> 1;
    const int sc = (tid & 1) * 16;

    for (int kt = 0; kt < K; kt += BK) {
        const float* gA = A + (size_t)(row0 + sr) * K + kt + sc;
        #pragma unroll
        for (int q = 0; q < 4; ++q) {
            float4 v = *(const float4*)(gA + q * 4);
            ushort4 h4, l4;
            split_bf(v.x, h4.x, l4.x);
            split_bf(v.y, h4.y, l4.y);
            split_bf(v.z, h4.z, l4.z);
            split_bf(v.w, h4.w, l4.w);
            *(ushort4*)&AsH[sr][sc + q * 4] = h4;
            *(ushort4*)&AsL[sr][sc + q * 4] = l4;
        }
        const int4* gBh = (const int4*)(Bth + (size_t)(col0 + sr) * K + kt + sc);
        *(int4*)&BsH[sr][sc]     = gBh[0];
        *(int4*)&BsH[sr][sc + 8] = gBh[1];
        const int4* gBl = (const int4*)(Btl + (size_t)(col0 + sr) * K + kt + sc);
        *(int4*)&BsL[sr][sc]     = gBl[0];
        *(int4*)&BsL[sr][sc + 8] = gBl[1];
        __syncthreads();

        const int r = lane & 15, kg = lane >> 4;
        bf16x8 ah[4], al[4], bh[4], bl[4];
        #pragma unroll
        for (int m = 0; m < 4; ++m) {
            ah[m] = *(const bf16x8*)&AsH[wr * 64 + m * 16 + r][kg * 8];
            al[m] = *(const bf16x8*)&AsL[wr * 64 + m * 16 + r][kg * 8];
        }
        #pragma unroll
        for (int n = 0; n < 4; ++n) {
            bh[n] = *(const bf16x8*)&BsH[wc * 64 + n * 16 + r][kg * 8];
            bl[n] = *(const bf16x8*)&BsL[wc * 64 + n * 16 + r][kg * 8];
        }
        #pragma unroll
        for (int m = 0; m < 4; ++m)
            #pragma unroll
            for (int n = 0; n < 4; ++n) {
                acc[m][n] = __builtin_amdgcn_mfma_f32_16x16x32_bf16(ah[m], bh[n], acc[m][n], 0, 0, 0);
                acc[m][n] = __builtin_amdgcn_mfma_f32_16x16x32_bf16(ah[m], bl[n], acc[m][n], 0, 0, 0);
                acc[m][n] = __builtin_amdgcn_mfma_f32_16x16x32_bf16(al[m], bh[n], acc[m][n], 0, 0, 0);
            }
        __syncthreads();
    }

    const int cl = lane & 15, rg = lane >> 4;
    #pragma unroll
    for (int n = 0; n < 4; ++n) {
        int gc = col0 + wc * 64 + n * 16 + cl;
        float bv = bias[gc];
        #pragma unroll
        for (int m = 0; m < 4; ++m) {
            int gr = row0 + wr * 64 + m * 16 + rg * 4;
            #pragma unroll
            for (int r2 = 0; r2 < 4; ++r2)
                C[(size_t)(gr + r2) * N + gc] = acc[m][n][r2] + bv;
        }
    }
}

// ---- phase 2: recurrence via MFMA. 64 WGs (1 row each), 512 threads, no cross-WG sync.
// Wave w owns k-eighth w. R as MFMA B-fragments: 26 col-tiles in registers
// (AGPR-friendly: MFMA reads AGPRs directly), 6 in LDS. A-fragment = h (row 0,
// rows 1-15 don't-care) built from in-register hval via ds_bpermute.
// One barrier per step; parity-double-buffered partials; r12 finalize.
__global__ __launch_bounds__(512, 2) void rnn_mfma_kernel(
    const uint* __restrict__ Rpk,    // [131072] packed fp16 B-fragments
    float* __restrict__ out,         // [B][T][H]: pre -> h in place
    float* __restrict__ hlast,       // [B][H]
    const float* __restrict__ h0)    // [B][H]
{
    __shared__ uint Rlds[NLDSCT * 2 * 2048];   // 96 KB
    __shared__ float part[2][8][Hdim];         // 32 KB, parity double-buffered

    const int tid = threadIdx.x;
    const int row = blockIdx.x;
    const int w   = tid >> 6;               // wave = k-eighth
    const int l   = tid & 63;
    const int li  = l & 31;
    const int fcol = w * 64 + 2 * li;       // finalize columns fcol, fcol+1

    // register-resident B-fragments: 26 ct x 2 kt x 4 dwords = 208 dwords
    uint4 breg[NREGCT][2];
    const uint* rb = Rpk + tid * 4;
    #pragma unroll
    for (int ct = 0; ct < NREGCT; ++ct) {
        breg[ct][0] = *(const uint4*)(rb + (0 * 32 + ct) * 2048);
        breg[ct][1] = *(const uint4*)(rb + (1 * 32 + ct) * 2048);
    }
    // LDS-resident B-fragments: ct in [26,32)
    #pragma unroll
    for (int ci = 0; ci < NLDSCT; ++ci)
        #pragma unroll
        for (int kt = 0; kt < 2; ++kt)
            *(uint4*)&Rlds[(ci * 2 + kt) * 2048 + tid * 4] =
                *(const uint4*)(rb + (kt * 32 + NREGCT + ci) * 2048);

    // h in-register: lane i<32 holds fp16 pair (cols w*64+2i, w*64+2i+1)
    uint hval = packf16(h0[row * Hdim + fcol], h0[row * Hdim + fcol + 1]);
    __syncthreads();

    float* orow = out + (size_t)row * Tdim * Hdim;
    float2 pre = *(const float2*)(orow + fcol);       // pre for t=0

    for (int t = 0; t < Tdim; ++t, orow += Hdim) {
        // prefetch pre for t+1 (orow[t+1] still holds untouched GEMM output)
        float2 pre_nxt = *(const float2*)(orow + Hdim + fcol);

        // A-fragments for kt=0,1: lane l needs h pairs kt*16 + (l>>4)*4 + q.
        // Only C row 0 (lanes 0-15) is consumed, so all-row-equal A is fine.
        const int pb = (l >> 4) * 4;
        uint4 a0u, a1u;
        a0u.x = __builtin_amdgcn_ds_bpermute((pb + 0) << 2, hval);
        a0u.y = __builtin_amdgcn_ds_bpermute((pb + 1) << 2, hval);
        a0u.z = __builtin_amdgcn_ds_bpermute((pb + 2) << 2, hval);
        a0u.w = __builtin_amdgcn_ds_bpermute((pb + 3) << 2, hval);
        a1u.x = __builtin_amdgcn_ds_bpermute((pb + 16) << 2, hval);
        a1u.y = __builtin_amdgcn_ds_bpermute((pb + 17) << 2, hval);
        a1u.z = __builtin_amdgcn_ds_bpermute((pb + 18) << 2, hval);
        a1u.w = __builtin_amdgcn_ds_bpermute((pb + 19) << 2, hval);
        f16x8 a0 = __builtin_bit_cast(f16x8, a0u);
        f16x8 a1 = __builtin_bit_cast(f16x8, a1u);

        const int p = t & 1;
        // register col-tiles: 2 chained MFMAs each
        #pragma unroll
        for (int ct = 0; ct < NREGCT; ++ct) {
            f32x4 acc = {};
            acc = __builtin_amdgcn_mfma_f32_16x16x32_f16(
                a0, __builtin_bit_cast(f16x8, breg[ct][0]), acc, 0, 0, 0);
            acc = __builtin_amdgcn_mfma_f32_16x16x32_f16(
                a1, __builtin_bit_cast(f16x8, breg[ct][1]), acc, 0, 0, 0);
            if (l < 16) part[p][w][ct * 16 + l] = acc[0];
        }
        // LDS col-tiles
        #pragma unroll
        for (int ci = 0; ci < NLDSCT; ++ci) {
            uint4 b0 = *(const uint4*)&Rlds[(ci * 2 + 0) * 2048 + tid * 4];
            uint4 b1 = *(const uint4*)&Rlds[(ci * 2 + 1) * 2048 + tid * 4];
            f32x4 acc = {};
            acc = __builtin_amdgcn_mfma_f32_16x16x32_f16(
                a0, __builtin_bit_cast(f16x8, b0), acc, 0, 0, 0);
            acc = __builtin_amdgcn_mfma_f32_16x16x32_f16(
                a1, __builtin_bit_cast(f16x8, b1), acc, 0, 0, 0);
            if (l < 16) part[p][w][(NREGCT + ci) * 16 + l] = acc[0];
        }
        __syncthreads();                                  // the ONLY barrier

        // finalize: all lanes compute cols fcol,fcol+1 (lanes>=32 redundant)
        float s0 = pre.x, s1 = pre.y;
        #pragma unroll
        for (int e = 0; e < 8; ++e) {
            float2 pp = *(const float2*)&part[p][e][fcol];
            s0 += pp.x; s1 += pp.y;
        }
        s0 = fminf(fmaxf(s0, -CLIPV), CLIPV);
        s1 = fminf(fmaxf(s1, -CLIPV), CLIPV);
        float e0 = __expf(2.0f * s0), e1 = __expf(2.0f * s1);
        float v0 = (e0 - 1.0f) * fastrcp(e0 + 1.0f);      // tanh
        float v1 = (e1 - 1.0f) * fastrcp(e1 + 1.0f);
        hval = pkrtz(v0, v1);                             // h stays in-register
        if (l < 32) {
            *(float2*)(orow + fcol) = make_float2(v0, v1);
            if (t == Tdim - 1)
                *(float2*)&hlast[row * Hdim + fcol] = make_float2(v0, v1);
        }
        pre = pre_nxt;
        // no second barrier: hval same-wave; part WAR parity-protected
    }
}

extern "C" void kernel_launch(void* const* d_in, const int* in_sizes, int n_in,
                              void* d_out, int out_size, void* d_ws, size_t ws_size,
                              hipStream_t stream) {
    const float* x    = (const float*)d_in[0];
    const float* W    = (const float*)d_in[1];
    const float* R    = (const float*)d_in[2];
    const float* bias = (const float*)d_in[3];
    const float* h0   = (const float*)d_in[4];
    float* out = (float*)d_out;

    ushort* wth = (ushort*)d_ws;                                // 512 KB
    ushort* wtl = wth + (size_t)Idim * Hdim;                    // 512 KB
    uint* rpk   = (uint*)((char*)d_ws + (1u << 20));            // 512 KB

    transpose_w_kernel<<<(Idim * Hdim + 255) / 256, 256, 0, stream>>>(W, wth, wtl);
    pack_r_kernel<<<512, 256, 0, stream>>>(R, rpk);

    dim3 gg(Bdim * Tdim / BM, Hdim / BN);
    gemm_xw<<<gg, 256, 0, stream>>>(x, wth, wtl, bias, out, Bdim * Tdim, Hdim, Idim);

    rnn_mfma_kernel<<<Bdim, 512, 0, stream>>>(
        rpk, out, out + (size_t)Bdim * Tdim * Hdim, h0);
}

// Round 14
// 786.606 us; speedup vs baseline: 1.3437x; 1.3437x over previous
//
#include <hip/hip_runtime.h>

#define Bdim 64
#define Tdim 512
#define Idim 512
#define Hdim 512
#define CLIPV 10.0f
#define NREGKT 12       // k-frags 0..11 per col-tile in registers (48 frags, 192 dw)
#define NLDSKT 4        // k-frags 12..15 in LDS (16 frags, 128 KB)

typedef __attribute__((ext_vector_type(4))) float f32x4;
typedef __attribute__((ext_vector_type(8))) short bf16x8;
typedef _Float16 f16x8 __attribute__((ext_vector_type(8)));

__device__ __forceinline__ ushort f2bf(float f) {
    unsigned u = __builtin_bit_cast(unsigned, f);
    u += 0x7fffu + ((u >> 16) & 1u);   // round-to-nearest-even
    return (ushort)(u >> 16);
}
__device__ __forceinline__ float bf2f(ushort h) {
    return __builtin_bit_cast(float, (unsigned)h << 16);
}
__device__ __forceinline__ void split_bf(float f, ushort& h, ushort& l) {
    h = f2bf(f);
    l = f2bf(f - bf2f(h));
}
__device__ __forceinline__ uint packf16(float a, float b) {
    _Float16 fa = (_Float16)a, fb = (_Float16)b;
    return (uint)__builtin_bit_cast(ushort, fa) |
           ((uint)__builtin_bit_cast(ushort, fb) << 16);
}
__device__ __forceinline__ ushort f2h(float f) {
    _Float16 h = (_Float16)f;
    return __builtin_bit_cast(ushort, h);
}
__device__ __forceinline__ float fastrcp(float x) {
#if __has_builtin(__builtin_amdgcn_rcpf)
    return __builtin_amdgcn_rcpf(x);
#else
    return 1.0f / x;
#endif
}

// ---- cast + transpose W into hi/lo bf16 (feed-forward GEMM operands) ----
__global__ __launch_bounds__(256) void transpose_w_kernel(const float* __restrict__ w,
                                                          ushort* __restrict__ wth,
                                                          ushort* __restrict__ wtl) {
    int idx = blockIdx.x * 256 + threadIdx.x;
    int k = idx >> 9, n = idx & 511;
    ushort h, l;
    split_bf(w[idx], h, l);
    wth[n * Idim + k] = h;
    wtl[n * Idim + k] = l;
}

// ---- pack R into MFMA B-fragments (fp16), full-k layout ----
// frag g = kt*32 + C  (kt: 32-k tile 0..15, C: 16-col tile 0..31).
// Lane l of the fragment holds B[k][col]: col = C*16 + (l&15),
// k = kt*32 + (l>>4)*8 + 2q (+1).   rpk[g*256 + l*4 + q].
__global__ __launch_bounds__(256) void pack_r_kernel(const float* __restrict__ Rw,
                                                     uint* __restrict__ rpk) {
    int d = blockIdx.x * 256 + threadIdx.x;      // 0..131071
    int g = d >> 8;                              // 0..511
    int kt = g >> 5, C = g & 31;
    int rem = d & 255;
    int l = rem >> 2, q = rem & 3;
    int col = C * 16 + (l & 15);
    int k = kt * 32 + (l >> 4) * 8 + 2 * q;
    rpk[d] = packf16(Rw[(size_t)k * Hdim + col],
                     Rw[(size_t)(k + 1) * Hdim + col]);
}

// ---- phase 1: pre = x @ W + bias via bf16x3 MFMA ----
#define BM 128
#define BN 128
#define BK 32
__global__ __launch_bounds__(256) void gemm_xw(
    const float* __restrict__ A,
    const ushort* __restrict__ Bth,
    const ushort* __restrict__ Btl,
    const float* __restrict__ bias,
    float* __restrict__ C,
    int M, int N, int K)
{
    __shared__ ushort AsH[BM][BK];
    __shared__ ushort AsL[BM][BK];
    __shared__ ushort BsH[BN][BK];
    __shared__ ushort BsL[BN][BK];
    int bm = blockIdx.x, bn = blockIdx.y;
    int tid = threadIdx.x;
    int wave = tid >> 6, lane = tid & 63;
    int wr = wave >> 1, wc = wave & 1;
    f32x4 acc[4][4] = {};
    const int row0 = bm * BM, col0 = bn * BN;
    const int sr = tid >> 1;
    const int sc = (tid & 1) * 16;

    for (int kt = 0; kt < K; kt += BK) {
        const float* gA = A + (size_t)(row0 + sr) * K + kt + sc;
        #pragma unroll
        for (int q = 0; q < 4; ++q) {
            float4 v = *(const float4*)(gA + q * 4);
            ushort4 h4, l4;
            split_bf(v.x, h4.x, l4.x);
            split_bf(v.y, h4.y, l4.y);
            split_bf(v.z, h4.z, l4.z);
            split_bf(v.w, h4.w, l4.w);
            *(ushort4*)&AsH[sr][sc + q * 4] = h4;
            *(ushort4*)&AsL[sr][sc + q * 4] = l4;
        }
        const int4* gBh = (const int4*)(Bth + (size_t)(col0 + sr) * K + kt + sc);
        *(int4*)&BsH[sr][sc]     = gBh[0];
        *(int4*)&BsH[sr][sc + 8] = gBh[1];
        const int4* gBl = (const int4*)(Btl + (size_t)(col0 + sr) * K + kt + sc);
        *(int4*)&BsL[sr][sc]     = gBl[0];
        *(int4*)&BsL[sr][sc + 8] = gBl[1];
        __syncthreads();

        const int r = lane & 15, kg = lane >> 4;
        bf16x8 ah[4], al[4], bh[4], bl[4];
        #pragma unroll
        for (int m = 0; m < 4; ++m) {
            ah[m] = *(const bf16x8*)&AsH[wr * 64 + m * 16 + r][kg * 8];
            al[m] = *(const bf16x8*)&AsL[wr * 64 + m * 16 + r][kg * 8];
        }
        #pragma unroll
        for (int n = 0; n < 4; ++n) {
            bh[n] = *(const bf16x8*)&BsH[wc * 64 + n * 16 + r][kg * 8];
            bl[n] = *(const bf16x8*)&BsL[wc * 64 + n * 16 + r][kg * 8];
        }
        #pragma unroll
        for (int m = 0; m < 4; ++m)
            #pragma unroll
            for (int n = 0; n < 4; ++n) {
                acc[m][n] = __builtin_amdgcn_mfma_f32_16x16x32_bf16(ah[m], bh[n], acc[m][n], 0, 0, 0);
                acc[m][n] = __builtin_amdgcn_mfma_f32_16x16x32_bf16(ah[m], bl[n], acc[m][n], 0, 0, 0);
                acc[m][n] = __builtin_amdgcn_mfma_f32_16x16x32_bf16(al[m], bh[n], acc[m][n], 0, 0, 0);
            }
        __syncthreads();
    }

    const int cl = lane & 15, rg = lane >> 4;
    #pragma unroll
    for (int n = 0; n < 4; ++n) {
        int gc = col0 + wc * 64 + n * 16 + cl;
        float bv = bias[gc];
        #pragma unroll
        for (int m = 0; m < 4; ++m) {
            int gr = row0 + wr * 64 + m * 16 + rg * 4;
            #pragma unroll
            for (int r2 = 0; r2 < 4; ++r2)
                C[(size_t)(gr + r2) * N + gc] = acc[m][n][r2] + bv;
        }
    }
}

// ---- phase 2: recurrence via full-k MFMA. 64 WGs (1 row each), 512 threads.
// Wave w owns cols [w*64, w*64+64) over ALL k: 4 col-tiles x 16 k-frags = 64
// MFMAs chained into 4 accumulators. Row 0 of C = complete dot product ->
// NO partial exchange, NO finalize sum. h crosses waves via h16[2][512] fp16
// in LDS (parity double-buffered, ONE barrier/step). B-frags: 48 in regs
// (AGPR overflow is free - MFMA reads AGPRs natively), 16 in LDS.
__global__ __launch_bounds__(512, 2) void rnn_mfma_kernel(
    const uint* __restrict__ Rpk,    // [131072] packed fp16 B-fragments
    float* __restrict__ out,         // [B][T][H]: pre -> h in place
    float* __restrict__ hlast,       // [B][H]
    const float* __restrict__ h0)    // [B][H]
{
    __shared__ uint Rlds[NLDSKT * 4 * 2048];   // 128 KB
    __shared__ ushort h16[2][Hdim];            // 2 KB

    const int tid = threadIdx.x;
    const int row = blockIdx.x;
    const int w   = tid >> 6;        // wave = col block [w*64, w*64+64)
    const int l   = tid & 63;
    const int lr  = l & 15;          // col-within-tile (C row 0 lane)
    const int kg  = l >> 4;          // k-group within fragment

    // register-resident B-fragments: kt 0..11 x 4 col-tiles = 192 dwords
    uint4 breg[NREGKT][4];
    const uint* rb = Rpk + l * 4;
    #pragma unroll
    for (int kt = 0; kt < NREGKT; ++kt)
        #pragma unroll
        for (int c = 0; c < 4; ++c)
            breg[kt][c] = *(const uint4*)(rb + (kt * 32 + w * 4 + c) * 256);
    // LDS-resident B-fragments: kt 12..15
    #pragma unroll
    for (int kt = 0; kt < NLDSKT; ++kt)
        #pragma unroll
        for (int c = 0; c < 4; ++c)
            *(uint4*)&Rlds[(kt * 4 + c) * 2048 + tid * 4] =
                *(const uint4*)(rb + ((NREGKT + kt) * 32 + w * 4 + c) * 256);

    h16[0][tid] = f2h(h0[row * Hdim + tid]);
    __syncthreads();

    float* orow = out + (size_t)row * Tdim * Hdim;
    float pre[4];
    #pragma unroll
    for (int c = 0; c < 4; ++c)
        pre[c] = orow[w * 64 + c * 16 + lr];

    for (int t = 0; t < Tdim; ++t, orow += Hdim) {
        const int p = t & 1;
        // prefetch pre for t+1 (orow[t+1] still untouched GEMM output;
        // at t=511 this reads into the hlast region of d_out - in bounds, unused)
        float pren[4];
        #pragma unroll
        for (int c = 0; c < 4; ++c)
            pren[c] = orow[Hdim + w * 64 + c * 16 + lr];

        f32x4 acc0 = {}, acc1 = {}, acc2 = {}, acc3 = {};
        #pragma unroll
        for (int kt = 0; kt < 16; ++kt) {
            // A-fragment: all-rows-equal h (row 0 is what we consume).
            // lane l reads h[kt*32 + kg*8 .. +7] - broadcast within 16-lane group.
            f16x8 a = *(const f16x8*)&h16[p][kt * 32 + kg * 8];
            if (kt < NREGKT) {
                acc0 = __builtin_amdgcn_mfma_f32_16x16x32_f16(
                    a, __builtin_bit_cast(f16x8, breg[kt][0]), acc0, 0, 0, 0);
                acc1 = __builtin_amdgcn_mfma_f32_16x16x32_f16(
                    a, __builtin_bit_cast(f16x8, breg[kt][1]), acc1, 0, 0, 0);
                acc2 = __builtin_amdgcn_mfma_f32_16x16x32_f16(
                    a, __builtin_bit_cast(f16x8, breg[kt][2]), acc2, 0, 0, 0);
                acc3 = __builtin_amdgcn_mfma_f32_16x16x32_f16(
                    a, __builtin_bit_cast(f16x8, breg[kt][3]), acc3, 0, 0, 0);
            } else {
                uint4 b0 = *(const uint4*)&Rlds[((kt - NREGKT) * 4 + 0) * 2048 + tid * 4];
                uint4 b1 = *(const uint4*)&Rlds[((kt - NREGKT) * 4 + 1) * 2048 + tid * 4];
                uint4 b2 = *(const uint4*)&Rlds[((kt - NREGKT) * 4 + 2) * 2048 + tid * 4];
                uint4 b3 = *(const uint4*)&Rlds[((kt - NREGKT) * 4 + 3) * 2048 + tid * 4];
                acc0 = __builtin_amdgcn_mfma_f32_16x16x32_f16(
                    a, __builtin_bit_cast(f16x8, b0), acc0, 0, 0, 0);
                acc1 = __builtin_amdgcn_mfma_f32_16x16x32_f16(
                    a, __builtin_bit_cast(f16x8, b1), acc1, 0, 0, 0);
                acc2 = __builtin_amdgcn_mfma_f32_16x16x32_f16(
                    a, __builtin_bit_cast(f16x8, b2), acc2, 0, 0, 0);
                acc3 = __builtin_amdgcn_mfma_f32_16x16x32_f16(
                    a, __builtin_bit_cast(f16x8, b3), acc3, 0, 0, 0);
            }
        }

        // finalize: lanes 0..15 hold C row 0 (reg 0) = full dot product
        if (l < 16) {
            float s[4] = {acc0[0], acc1[0], acc2[0], acc3[0]};
            #pragma unroll
            for (int c = 0; c < 4; ++c) {
                float g = s[c] + pre[c];
                g = fminf(fmaxf(g, -CLIPV), CLIPV);
                float e = __expf(2.0f * g);
                float v = (e - 1.0f) * fastrcp(e + 1.0f);   // tanh
                int col = w * 64 + c * 16 + l;
                h16[p ^ 1][col] = f2h(v);
                orow[col] = v;
                if (t == Tdim - 1) hlast[row * Hdim + col] = v;
            }
        }
        __syncthreads();   // the ONLY barrier: h(t) visible; WAR parity-safe
        #pragma unroll
        for (int c = 0; c < 4; ++c) pre[c] = pren[c];
    }
}

extern "C" void kernel_launch(void* const* d_in, const int* in_sizes, int n_in,
                              void* d_out, int out_size, void* d_ws, size_t ws_size,
                              hipStream_t stream) {
    const float* x    = (const float*)d_in[0];
    const float* W    = (const float*)d_in[1];
    const float* R    = (const float*)d_in[2];
    const float* bias = (const float*)d_in[3];
    const float* h0   = (const float*)d_in[4];
    float* out = (float*)d_out;

    ushort* wth = (ushort*)d_ws;                                // 512 KB
    ushort* wtl = wth + (size_t)Idim * Hdim;                    // 512 KB
    uint* rpk   = (uint*)((char*)d_ws + (1u << 20));            // 512 KB

    transpose_w_kernel<<<(Idim * Hdim + 255) / 256, 256, 0, stream>>>(W, wth, wtl);
    pack_r_kernel<<<512, 256, 0, stream>>>(R, rpk);

    dim3 gg(Bdim * Tdim / BM, Hdim / BN);
    gemm_xw<<<gg, 256, 0, stream>>>(x, wth, wtl, bias, out, Bdim * Tdim, Hdim, Idim);

    rnn_mfma_kernel<<<Bdim, 512, 0, stream>>>(
        rpk, out, out + (size_t)Bdim * Tdim * Hdim, h0);
}